// Round 7
// baseline (464.703 us; speedup 1.0000x reference)
//
#include <hip/hip_runtime.h>

typedef unsigned short u16;
typedef unsigned int u32;

typedef float f4 __attribute__((ext_vector_type(4)));
typedef short s8v __attribute__((ext_vector_type(8)));
typedef u16 us8 __attribute__((ext_vector_type(8)));
typedef _Float16 h4 __attribute__((ext_vector_type(4)));
typedef __fp16 g2 __attribute__((ext_vector_type(2)));

__device__ __forceinline__ u16 f2bf(float x){ u32 b=__float_as_uint(x); b += 0x7FFFu + ((b>>16)&1u); return (u16)(b>>16); }
__device__ __forceinline__ u16 f2h(float x){ union{_Float16 h; u16 u;} c; c.h=(_Float16)x; return c.u; }

// ---- workspace byte offsets (bar counters live at 0..255) ----
#define O_XRT  4096u                     // bf16 xrTp [4][34*34 pix][256 c] (zero halo)
#define O_WPT  (O_XRT + 2367488u)        // bf16 conv A, 4 parity classes [192][Kp]
#define O_QH   (O_WPT + 884736u)         // f16  q (pre-scaled) [4][4225 pix][64 d]
#define O_KT   (O_QH  + 2163200u)        // f16  k [b][h][1024 key][8 d]
#define O_V    (O_KT  + 524288u)         // f16  v [b][64 dv][1024 key]
#define O_ATT  (O_V   + 524288u)         // bf16 attT [4][4225][64 dv]
#define O_WKV  (O_ATT + 2163200u)        // bf16 [128][256]
#define O_WO2  (O_WKV + 65536u)          // bf16 [128][64]

#define NBLK 1024

__device__ __forceinline__ void gbar(u32* c) {
  __syncthreads();
  if (threadIdx.x == 0) {
    __threadfence();
    atomicAdd(c, 1u);
    while (atomicAdd(c, 0u) < (u32)NBLK) __builtin_amdgcn_s_sleep(4);
    __threadfence();
  }
  __syncthreads();
}

// ---------- conv class body (R5-proven: mb-split, padded halo, dbuf 1-barrier) ----------
template<int PY,int PX,int TT>
__device__ __forceinline__ void conv_cls(
    const u16* __restrict__ xrTp, const u16* __restrict__ wcls,
    float* __restrict__ outF, u16* __restrict__ qh,
    int mb, int nb, u16* Blds)
{
  constexpr int Hy = 33 - PY, Wx = 33 - PX;
  constexpr int NC = 4*Hy*Wx;
  constexpr int KP = TT*256;
  constexpr int NKT = KP/64;
  int tid = threadIdx.x;
  int lane = tid & 63, wv = tid >> 6, quad = lane >> 4, c15 = lane & 15;
  int sn = tid >> 2, sg = tid & 3;
  int n_g = nb*64 + sn;
  int ncl = n_g < NC ? n_g : NC-1;
  int bb = ncl/(Hy*Wx); int rem = ncl - bb*(Hy*Wx); int yq = rem/Wx; int xq = rem - yq*Wx;
  const u16* bsrc = xrTp + (((size_t)(bb*1156 + (yq+1)*34 + xq+1))<<8) + sg*16;
  f4 acc[4];
  #pragma unroll
  for (int i=0;i<4;i++) acc[i] = (f4){0.f,0.f,0.f,0.f};
  const u16* arow = wcls + (size_t)(mb*64 + wv*16 + c15)*KP + quad*8;
  auto loadB = [&](int kt, us8& v0, us8& v1) {
    int tt = kt >> 2, c0 = (kt & 3)*64;
    int dy, dx;
    if (TT==4){ dy = tt>>1; dx = tt&1; }
    else if (TT==2){ if (PX==1){ dy=tt; dx=0; } else { dy=0; dx=tt; } }
    else { dy=0; dx=0; }
    const u16* p = bsrc - (((dy*34+dx))<<8) + c0;
    v0 = *(const us8*)p;
    v1 = *(const us8*)(p+8);
  };
  us8 cv0, cv1; loadB(0, cv0, cv1);
  int pb = 0;
  for (int kt = 0; kt < NKT; ++kt) {
    u16* Bw = Blds + pb*4608;
    *(us8*)(Bw + sn*72 + sg*16) = cv0;
    *(us8*)(Bw + sn*72 + sg*16 + 8) = cv1;
    __syncthreads();
    if (kt + 1 < NKT) loadB(kt+1, cv0, cv1);
    s8v a0 = *(const s8v*)(arow + kt*64);
    s8v a1 = *(const s8v*)(arow + kt*64 + 32);
    #pragma unroll
    for (int t4=0;t4<4;t4++) {
      const u16* br = Blds + pb*4608 + (t4*16 + c15)*72 + quad*8;
      s8v bf0 = *(const s8v*)br;
      s8v bf1 = *(const s8v*)(br + 32);
      acc[t4] = __builtin_amdgcn_mfma_f32_16x16x32_bf16(a0, bf0, acc[t4], 0, 0, 0);
      acc[t4] = __builtin_amdgcn_mfma_f32_16x16x32_bf16(a1, bf1, acc[t4], 0, 0, 0);
    }
    pb ^= 1;
  }
  #pragma unroll
  for (int t4=0;t4<4;t4++) {
    int n2 = nb*64 + t4*16 + c15;
    if (n2 < NC) {
      int bb2 = n2/(Hy*Wx); int rem2 = n2 - bb2*(Hy*Wx); int yq2 = rem2/Wx; int xq2 = rem2 - yq2*Wx;
      int pix = (2*yq2 + PY)*65 + (2*xq2 + PX);
      if (mb < 2) {
        int mrow = mb*64 + wv*16 + quad*4;
        #pragma unroll
        for (int rg=0; rg<4; rg++)
          outF[(size_t)(bb2*128 + mrow + rg)*4225 + pix] = acc[t4][rg];
      } else {
        int dv = wv*16 + quad*4;
        u16 pk[4];
        #pragma unroll
        for (int rg=0; rg<4; rg++) pk[rg] = f2h(acc[t4][rg]);
        *(uint2*)(qh + (((size_t)(bb2*4225 + pix))<<6) + dv) = *(uint2*)pk;
      }
    }
  }
}

// =================== mega-kernel: prep | conv+kv | attn | proj ===================
__global__ __launch_bounds__(256, 4) void k_mega(
    const float* __restrict__ x, const float* __restrict__ gamma, const float* __restrict__ beta,
    const float* __restrict__ mean, const float* __restrict__ var,
    const float* __restrict__ w_sc, const float* __restrict__ w_q,
    const float* __restrict__ w_k, const float* __restrict__ w_v, const float* __restrict__ w_o,
    char* __restrict__ ws, float* __restrict__ outF)
{
  __shared__ __align__(16) char SM[35072];
  u32* bar = (u32*)ws;
  u16* xrTp = (u16*)(ws + O_XRT);
  u16* wpt  = (u16*)(ws + O_WPT);
  u16* qh   = (u16*)(ws + O_QH);
  u16* kT   = (u16*)(ws + O_KT);
  u16* vbuf = (u16*)(ws + O_V);
  u16* attT = (u16*)(ws + O_ATT);
  u16* wkv  = (u16*)(ws + O_WKV);
  u16* wo2  = (u16*)(ws + O_WO2);
  int bid = blockIdx.x, tid = threadIdx.x;

  // ---------------- phase 0: BN+ReLU transpose (padded) + weight re-layouts ----------------
  {
    float* SS = (float*)SM; float* SH = SS + 64; u16* T = (u16*)(SH + 64);
    for (int u = bid; u < 2466; u += NBLK) {
      if (u < 512) {
        int b = u >> 7, pt = (u >> 2) & 31, ch = u & 3;
        int pix0 = pt*32, c0 = ch*64;
        if (tid < 64) {
          int c = c0 + tid;
          float s = gamma[c]*rsqrtf(var[c] + 1e-5f);
          SS[tid] = s; SH[tid] = beta[c] - mean[c]*s;
        }
        __syncthreads();
        int pix_l = tid & 31, c_l = tid >> 5;
        #pragma unroll
        for (int it = 0; it < 8; ++it) {
          int cl = it*8 + c_l;
          float v = x[(((size_t)(b*256 + c0 + cl))<<10) + pix0 + pix_l];
          T[pix_l*72 + cl] = f2bf(fmaxf(v*SS[cl] + SH[cl], 0.f));
        }
        __syncthreads();
        int pix_r = tid >> 3, j = tid & 7;
        us8 v0 = *(const us8*)(T + pix_r*72 + j*8);
        u16* dst = xrTp + (((size_t)(b*1156 + (pt+1)*34 + 1 + pix_r))<<8) + c0;
        *(us8*)(dst + j*8) = v0;
        __syncthreads();
      } else {
        int wid = (u - 512)*256 + tid;
        if (wid < 442368) {
          // jax conv_transpose (no flip): ky=0->(py0,dy1); ky=1->(py1,dy0); ky=2->(py0,dy0)
          int c, m, ky, kx; float val;
          if (wid < 294912) {
            c = wid / 1152; int r = wid - c*1152; m = r / 9; int t9 = r - m*9; ky = t9/3; kx = t9 - ky*3;
            val = w_sc[wid];
          } else {
            int i2 = wid - 294912;
            c = i2 / 576; int r = i2 - c*576; m = r / 9; int t9 = r - m*9; ky = t9/3; kx = t9 - ky*3;
            val = w_q[i2] * 0.51007023f;   // log2(e)/sqrt(8) folded
            m += 128;
          }
          int py = (ky==1) ? 1 : 0; int dy = (ky==0) ? 1 : 0;
          int px = (kx==1) ? 1 : 0; int dx = (kx==0) ? 1 : 0;
          int cls = py*2 + px;
          int tt, KP, base;
          if (cls==0){ tt = dy*2+dx; KP=1024; base=0; }
          else if (cls==1){ tt = dy; KP=512; base=196608; }
          else if (cls==2){ tt = dx; KP=512; base=294912; }
          else { tt = 0; KP=256; base=393216; }
          wpt[base + m*KP + tt*256 + c] = f2bf(val);
        } else if (wid < 475136) {
          int i = wid - 442368; int m = i >> 8, c = i & 255;
          float vv = (m < 64) ? w_k[m*256 + c] : w_v[(m-64)*256 + c];
          wkv[m*256 + c] = f2bf(vv);
        } else if (wid < 483328) {
          int i = wid - 475136;
          wo2[i] = f2bf(w_o[i]);
        } else if (wid < 500224) {
          int i = wid - 483328;                // halo zero
          int b = i / 4224; int r = i - b*4224;
          int hp = r >> 5, j = r & 31;
          int p;
          if (hp < 34) p = hp;
          else if (hp < 68) p = 33*34 + (hp - 34);
          else if (hp < 100) p = (hp - 68 + 1)*34;
          else p = (hp - 100 + 1)*34 + 33;
          *(us8*)(xrTp + (((size_t)(b*1156 + p))<<8) + j*8) = (us8)0;
        }
      }
    }
  }
  gbar(bar + 0);

  // ---------------- phase 1: conv-transpose GEMMs + k/v GEMM ----------------
  {
    u16* Blds = (u16*)SM;
    for (int u = bid; u < 923; u += NBLK) {
      if (u < 795) {
        int mb = u % 3, cy = u / 3;
        if (cy < 69)       conv_cls<0,0,4>(xrTp, wpt,          outF, qh, mb, cy,     Blds);
        else if (cy < 135) conv_cls<0,1,2>(xrTp, wpt + 196608, outF, qh, mb, cy-69,  Blds);
        else if (cy < 201) conv_cls<1,0,2>(xrTp, wpt + 294912, outF, qh, mb, cy-135, Blds);
        else               conv_cls<1,1,1>(xrTp, wpt + 393216, outF, qh, mb, cy-201, Blds);
      } else {
        int t = u - 795;
        int mb = t & 1, nb = t >> 1;
        int lane = tid & 63, wv = tid >> 6, quad = lane >> 4, c15 = lane & 15;
        int sn = tid >> 2, sg = tid & 3;
        int n_g = nb*64 + sn;
        int b0 = n_g >> 10, pix0 = n_g & 1023, y0 = pix0 >> 5, x0 = pix0 & 31;
        const u16* bsrc = xrTp + (((size_t)(b0*1156 + (y0+1)*34 + x0+1))<<8) + sg*16;
        f4 acc[4];
        #pragma unroll
        for (int i=0;i<4;i++) acc[i] = (f4){0.f,0.f,0.f,0.f};
        const u16* arow = wkv + (size_t)(mb*64 + wv*16 + c15)*256 + quad*8;
        us8 cv0 = *(const us8*)bsrc, cv1 = *(const us8*)(bsrc + 8);
        int pb = 0;
        for (int kt = 0; kt < 4; ++kt) {
          u16* Bw = Blds + pb*4608;
          *(us8*)(Bw + sn*72 + sg*16) = cv0;
          *(us8*)(Bw + sn*72 + sg*16 + 8) = cv1;
          __syncthreads();
          if (kt < 3) { cv0 = *(const us8*)(bsrc + (kt+1)*64); cv1 = *(const us8*)(bsrc + (kt+1)*64 + 8); }
          s8v a0 = *(const s8v*)(arow + kt*64);
          s8v a1 = *(const s8v*)(arow + kt*64 + 32);
          #pragma unroll
          for (int t4=0;t4<4;t4++) {
            const u16* br = Blds + pb*4608 + (t4*16 + c15)*72 + quad*8;
            s8v bf0 = *(const s8v*)br;
            s8v bf1 = *(const s8v*)(br + 32);
            acc[t4] = __builtin_amdgcn_mfma_f32_16x16x32_bf16(a0, bf0, acc[t4], 0, 0, 0);
            acc[t4] = __builtin_amdgcn_mfma_f32_16x16x32_bf16(a1, bf1, acc[t4], 0, 0, 0);
          }
          pb ^= 1;
        }
        int ml = wv*16 + quad*4;
        #pragma unroll
        for (int t4=0;t4<4;t4++) {
          int n2 = nb*64 + t4*16 + c15;
          int b = n2 >> 10, pix = n2 & 1023;
          if (mb == 0) {
            int h = ml >> 3, d0 = ml & 7;
            u16 pk[4];
            #pragma unroll
            for (int rg=0; rg<4; rg++) pk[rg] = f2h(acc[t4][rg]);
            *(uint2*)(kT + ((size_t)(b*8+h)<<13) + pix*8 + d0) = *(uint2*)pk;
          } else {
            #pragma unroll
            for (int rg=0; rg<4; rg++)
              vbuf[(((size_t)(b*64 + ml + rg))<<10) + pix] = f2h(acc[t4][rg]);
          }
        }
      }
      __syncthreads();
    }
  }
  gbar(bar + 1);

  // ---------------- phase 2: attention (no-max softmax, 2 q-tiles/wave) ----------------
  {
    u16* KL = (u16*)SM;
    u16* VL = KL + 8192;
    int lane = tid & 63, wv = tid >> 6, quad = lane >> 4, c15 = lane & 15;
    for (int u = bid; u < 1088; u += NBLK) {
      int qt = u % 34, bh = u / 34;
      int b = bh >> 3, h = bh & 7;
      {
        const uint4* kg = (const uint4*)(kT + ((size_t)bh << 13));
        for (int i = tid; i < 1024; i += 256) ((uint4*)KL)[i] = kg[i];
        const u16* vg = vbuf + ((size_t)(b*64 + h*8) << 10);
        for (int i = tid; i < 1024; i += 256) {
          int dv = i >> 7, k8 = (i & 127) << 3;
          *(uint4*)(VL + dv*1032 + k8) = *(const uint4*)(vg + (dv<<10) + k8);
        }
        if (tid < 129) {
          us8 ones;
          #pragma unroll
          for (int i=0;i<8;i++) ones[i] = 0x3C00;
          *(us8*)(VL + 8*1032 + tid*8) = ones;
        }
      }
      __syncthreads();
      int q0 = qt*128 + wv*32 + c15;
      int q1 = q0 + 16;
      int qa = q0 < 4224 ? q0 : 4224;
      int qb = q1 < 4224 ? q1 : 4224;
      uint2 t0 = *(const uint2*)(qh + (((size_t)(b*4225 + qa))<<6) + h*8 + (quad&1)*4);
      uint2 t1 = *(const uint2*)(qh + (((size_t)(b*4225 + qb))<<6) + h*8 + (quad&1)*4);
      h4 bq0 = quad < 2 ? *(h4*)&t0 : (h4)(_Float16)0.f;
      h4 bq1 = quad < 2 ? *(h4*)&t1 : (h4)(_Float16)0.f;
      const u16* klb = KL + c15*8 + (quad&1)*4;
      int vr = c15 > 8 ? 8 : c15;
      const u16* vlb = VL + vr*1032 + quad*4;
      const f4 zf = {0.f,0.f,0.f,0.f};
      f4 O0 = {0.f,0.f,0.f,0.f}, O1 = {0.f,0.f,0.f,0.f};
      union HU { uint2 u; h4 h; };
      #pragma unroll 8
      for (int kt=0; kt<64; ++kt) {
        h4 ak = *(const h4*)(klb + kt*128);
        h4 av = *(const h4*)(vlb + kt*16);
        f4 s0 = __builtin_amdgcn_mfma_f32_16x16x16f16(ak, bq0, zf, 0, 0, 0);
        f4 s1 = __builtin_amdgcn_mfma_f32_16x16x16f16(ak, bq1, zf, 0, 0, 0);
        g2 p0l = __builtin_amdgcn_cvt_pkrtz(__builtin_amdgcn_exp2f(s0[0]), __builtin_amdgcn_exp2f(s0[1]));
        g2 p0h = __builtin_amdgcn_cvt_pkrtz(__builtin_amdgcn_exp2f(s0[2]), __builtin_amdgcn_exp2f(s0[3]));
        g2 p1l = __builtin_amdgcn_cvt_pkrtz(__builtin_amdgcn_exp2f(s1[0]), __builtin_amdgcn_exp2f(s1[1]));
        g2 p1h = __builtin_amdgcn_cvt_pkrtz(__builtin_amdgcn_exp2f(s1[2]), __builtin_amdgcn_exp2f(s1[3]));
        HU u0; u0.u.x = __builtin_bit_cast(u32, p0l); u0.u.y = __builtin_bit_cast(u32, p0h);
        HU u1; u1.u.x = __builtin_bit_cast(u32, p1l); u1.u.y = __builtin_bit_cast(u32, p1h);
        O0 = __builtin_amdgcn_mfma_f32_16x16x16f16(av, u0.h, O0, 0, 0, 0);
        O1 = __builtin_amdgcn_mfma_f32_16x16x16f16(av, u1.h, O1, 0, 0, 0);
      }
      float l0 = __shfl(O0[0], 32 + c15, 64);
      float l1 = __shfl(O1[0], 32 + c15, 64);
      float r0 = __builtin_amdgcn_rcpf(l0);
      float r1 = __builtin_amdgcn_rcpf(l1);
      if (quad < 2) {
        if (q0 < 4225) {
          u16 pk[4];
          #pragma unroll
          for (int rg=0;rg<4;rg++) pk[rg] = f2bf(O0[rg]*r0);
          *(uint2*)(attT + (((size_t)(b*4225 + q0))<<6) + h*8 + quad*4) = *(uint2*)pk;
        }
        if (q1 < 4225) {
          u16 pk[4];
          #pragma unroll
          for (int rg=0;rg<4;rg++) pk[rg] = f2bf(O1[rg]*r1);
          *(uint2*)(attT + (((size_t)(b*4225 + q1))<<6) + h*8 + quad*4) = *(uint2*)pk;
        }
      }
      __syncthreads();
    }
  }
  gbar(bar + 2);

  // ---------------- phase 3: output projection + shortcut add ----------------
  {
    int lane = tid & 63, wv = tid >> 6, quad = lane >> 4, c15 = lane & 15;
    for (int u = bid; u < 268; u += NBLK) {
      int nbi = u % 67, b = u / 67;
      f4 acc[2][4];
      #pragma unroll
      for (int am=0;am<2;am++)
        #pragma unroll
        for (int i=0;i<4;i++) acc[am][i] = (f4){0.f,0.f,0.f,0.f};
      #pragma unroll
      for (int kt = 0; kt < 2; ++kt) {
        s8v a0 = *(const s8v*)(wo2 + (size_t)(wv*32 + c15)*64 + kt*32 + quad*8);
        s8v a1 = *(const s8v*)(wo2 + (size_t)(wv*32 + 16 + c15)*64 + kt*32 + quad*8);
        #pragma unroll
        for (int t4=0;t4<4;t4++) {
          int n = nbi*64 + t4*16 + c15;
          int nc = n < 4224 ? n : 4224;
          s8v bf = *(const s8v*)(attT + (((size_t)(b*4225 + nc))<<6) + kt*32 + quad*8);
          acc[0][t4] = __builtin_amdgcn_mfma_f32_16x16x32_bf16(a0, bf, acc[0][t4], 0, 0, 0);
          acc[1][t4] = __builtin_amdgcn_mfma_f32_16x16x32_bf16(a1, bf, acc[1][t4], 0, 0, 0);
        }
      }
      #pragma unroll
      for (int am=0;am<2;am++) {
        int mrow = wv*32 + am*16 + quad*4;
        #pragma unroll
        for (int t4=0;t4<4;t4++) {
          int n2 = nbi*64 + t4*16 + c15;
          if (n2 < 4225) {
            float* op = outF + (size_t)(b*128 + mrow)*4225 + n2;
            #pragma unroll
            for (int rg=0; rg<4; rg++) op[(size_t)rg*4225] += acc[am][t4][rg];
          }
        }
      }
    }
  }
}

extern "C" void kernel_launch(void* const* d_in, const int* in_sizes, int n_in,
                              void* d_out, int out_size, void* d_ws, size_t ws_size,
                              hipStream_t stream) {
  const float* x     = (const float*)d_in[0];
  const float* gamma = (const float*)d_in[1];
  const float* beta  = (const float*)d_in[2];
  const float* mean  = (const float*)d_in[3];
  const float* var   = (const float*)d_in[4];
  const float* w_sc  = (const float*)d_in[5];
  const float* w_q   = (const float*)d_in[6];
  const float* w_k   = (const float*)d_in[7];
  const float* w_v   = (const float*)d_in[8];
  const float* w_o   = (const float*)d_in[9];
  char* ws = (char*)d_ws;
  float* outF = (float*)d_out;

  hipMemsetAsync(ws, 0, 256, stream);   // zero the grid-barrier counters
  k_mega<<<NBLK, 256, 0, stream>>>(x, gamma, beta, mean, var, w_sc, w_q, w_k, w_v, w_o,
                                   ws, outF);
}

// Round 8
// 459.996 us; speedup vs baseline: 1.0102x; 1.0102x over previous
//
#include <hip/hip_runtime.h>

typedef unsigned short u16;
typedef unsigned int u32;

typedef float f4 __attribute__((ext_vector_type(4)));
typedef short s8v __attribute__((ext_vector_type(8)));
typedef u16 us8 __attribute__((ext_vector_type(8)));
typedef _Float16 h4 __attribute__((ext_vector_type(4)));
typedef __fp16 g2 __attribute__((ext_vector_type(2)));

__device__ __forceinline__ u16 f2bf(float x){ u32 b=__float_as_uint(x); b += 0x7FFFu + ((b>>16)&1u); return (u16)(b>>16); }
__device__ __forceinline__ u16 f2h(float x){ union{_Float16 h; u16 u;} c; c.h=(_Float16)x; return c.u; }

// ---- workspace byte offsets (bar counters live at 0..255) ----
#define O_XRT  4096u                     // bf16 xrTp [4][34*34 pix][256 c] (zero halo)
#define O_WPT  (O_XRT + 2367488u)        // bf16 conv A, 4 parity classes [192][Kp]
#define O_QH   (O_WPT + 884736u)         // f16  q (pre-scaled) [4][4225 pix][64 d]
#define O_KT   (O_QH  + 2163200u)        // f16  k [b][h][1024 key][8 d]
#define O_V    (O_KT  + 524288u)         // f16  v [b][64 dv][1024 key]
#define O_ATT  (O_V   + 524288u)         // bf16 attT [4][4225][64 dv]
#define O_WKV  (O_ATT + 2163200u)        // bf16 [128][256]
#define O_WO2  (O_WKV + 65536u)          // bf16 [128][64]

#define NBLK 1024

// arrive: one RMW per block. wait: relaxed agent-scope LOAD spin (non-serializing),
// s_sleep backoff. Fence pattern identical to R7 (correctness-proven on gfx950).
__device__ __forceinline__ void gbar(u32* c) {
  __syncthreads();
  if (threadIdx.x == 0) {
    __threadfence();
    atomicAdd(c, 1u);
    u32 v = __hip_atomic_load(c, __ATOMIC_RELAXED, __HIP_MEMORY_SCOPE_AGENT);
    while (v < (u32)NBLK) {
      __builtin_amdgcn_s_sleep(8);
      v = __hip_atomic_load(c, __ATOMIC_RELAXED, __HIP_MEMORY_SCOPE_AGENT);
    }
    __threadfence();
  }
  __syncthreads();
}

// ---------- conv class body (R5-proven: mb-split, padded halo, dbuf 1-barrier) ----------
template<int PY,int PX,int TT>
__device__ __forceinline__ void conv_cls(
    const u16* __restrict__ xrTp, const u16* __restrict__ wcls,
    float* __restrict__ outF, u16* __restrict__ qh,
    int mb, int nb, u16* Blds)
{
  constexpr int Hy = 33 - PY, Wx = 33 - PX;
  constexpr int NC = 4*Hy*Wx;
  constexpr int KP = TT*256;
  constexpr int NKT = KP/64;
  int tid = threadIdx.x;
  int lane = tid & 63, wv = tid >> 6, quad = lane >> 4, c15 = lane & 15;
  int sn = tid >> 2, sg = tid & 3;
  int n_g = nb*64 + sn;
  int ncl = n_g < NC ? n_g : NC-1;
  int bb = ncl/(Hy*Wx); int rem = ncl - bb*(Hy*Wx); int yq = rem/Wx; int xq = rem - yq*Wx;
  const u16* bsrc = xrTp + (((size_t)(bb*1156 + (yq+1)*34 + xq+1))<<8) + sg*16;
  f4 acc[4];
  #pragma unroll
  for (int i=0;i<4;i++) acc[i] = (f4){0.f,0.f,0.f,0.f};
  const u16* arow = wcls + (size_t)(mb*64 + wv*16 + c15)*KP + quad*8;
  auto loadB = [&](int kt, us8& v0, us8& v1) {
    int tt = kt >> 2, c0 = (kt & 3)*64;
    int dy, dx;
    if (TT==4){ dy = tt>>1; dx = tt&1; }
    else if (TT==2){ if (PX==1){ dy=tt; dx=0; } else { dy=0; dx=tt; } }
    else { dy=0; dx=0; }
    const u16* p = bsrc - (((dy*34+dx))<<8) + c0;
    v0 = *(const us8*)p;
    v1 = *(const us8*)(p+8);
  };
  us8 cv0, cv1; loadB(0, cv0, cv1);
  int pb = 0;
  for (int kt = 0; kt < NKT; ++kt) {
    u16* Bw = Blds + pb*4608;
    *(us8*)(Bw + sn*72 + sg*16) = cv0;
    *(us8*)(Bw + sn*72 + sg*16 + 8) = cv1;
    __syncthreads();
    if (kt + 1 < NKT) loadB(kt+1, cv0, cv1);
    s8v a0 = *(const s8v*)(arow + kt*64);
    s8v a1 = *(const s8v*)(arow + kt*64 + 32);
    #pragma unroll
    for (int t4=0;t4<4;t4++) {
      const u16* br = Blds + pb*4608 + (t4*16 + c15)*72 + quad*8;
      s8v bf0 = *(const s8v*)br;
      s8v bf1 = *(const s8v*)(br + 32);
      acc[t4] = __builtin_amdgcn_mfma_f32_16x16x32_bf16(a0, bf0, acc[t4], 0, 0, 0);
      acc[t4] = __builtin_amdgcn_mfma_f32_16x16x32_bf16(a1, bf1, acc[t4], 0, 0, 0);
    }
    pb ^= 1;
  }
  #pragma unroll
  for (int t4=0;t4<4;t4++) {
    int n2 = nb*64 + t4*16 + c15;
    if (n2 < NC) {
      int bb2 = n2/(Hy*Wx); int rem2 = n2 - bb2*(Hy*Wx); int yq2 = rem2/Wx; int xq2 = rem2 - yq2*Wx;
      int pix = (2*yq2 + PY)*65 + (2*xq2 + PX);
      if (mb < 2) {
        int mrow = mb*64 + wv*16 + quad*4;
        #pragma unroll
        for (int rg=0; rg<4; rg++)
          outF[(size_t)(bb2*128 + mrow + rg)*4225 + pix] = acc[t4][rg];
      } else {
        int dv = wv*16 + quad*4;
        u16 pk[4];
        #pragma unroll
        for (int rg=0; rg<4; rg++) pk[rg] = f2h(acc[t4][rg]);
        *(uint2*)(qh + (((size_t)(bb2*4225 + pix))<<6) + dv) = *(uint2*)pk;
      }
    }
  }
}

// =================== mega-kernel: prep | conv+kv | attn | proj ===================
__global__ __launch_bounds__(256, 4) void k_mega(
    const float* __restrict__ x, const float* __restrict__ gamma, const float* __restrict__ beta,
    const float* __restrict__ mean, const float* __restrict__ var,
    const float* __restrict__ w_sc, const float* __restrict__ w_q,
    const float* __restrict__ w_k, const float* __restrict__ w_v, const float* __restrict__ w_o,
    char* __restrict__ ws, float* __restrict__ outF)
{
  __shared__ __align__(16) char SM[35072];
  u32* bar = (u32*)ws;
  u16* xrTp = (u16*)(ws + O_XRT);
  u16* wpt  = (u16*)(ws + O_WPT);
  u16* qh   = (u16*)(ws + O_QH);
  u16* kT   = (u16*)(ws + O_KT);
  u16* vbuf = (u16*)(ws + O_V);
  u16* attT = (u16*)(ws + O_ATT);
  u16* wkv  = (u16*)(ws + O_WKV);
  u16* wo2  = (u16*)(ws + O_WO2);
  int bid = blockIdx.x, tid = threadIdx.x;

  // ---------------- phase 0: BN+ReLU transpose (padded) + weight re-layouts ----------------
  {
    float* SS = (float*)SM; float* SH = SS + 64; u16* T = (u16*)(SH + 64);
    for (int u = bid; u < 2466; u += NBLK) {
      if (u < 512) {
        int b = u >> 7, pt = (u >> 2) & 31, ch = u & 3;
        int pix0 = pt*32, c0 = ch*64;
        if (tid < 64) {
          int c = c0 + tid;
          float s = gamma[c]*rsqrtf(var[c] + 1e-5f);
          SS[tid] = s; SH[tid] = beta[c] - mean[c]*s;
        }
        __syncthreads();
        int pix_l = tid & 31, c_l = tid >> 5;
        #pragma unroll
        for (int it = 0; it < 8; ++it) {
          int cl = it*8 + c_l;
          float v = x[(((size_t)(b*256 + c0 + cl))<<10) + pix0 + pix_l];
          T[pix_l*72 + cl] = f2bf(fmaxf(v*SS[cl] + SH[cl], 0.f));
        }
        __syncthreads();
        int pix_r = tid >> 3, j = tid & 7;
        us8 v0 = *(const us8*)(T + pix_r*72 + j*8);
        u16* dst = xrTp + (((size_t)(b*1156 + (pt+1)*34 + 1 + pix_r))<<8) + c0;
        *(us8*)(dst + j*8) = v0;
        __syncthreads();
      } else {
        int wid = (u - 512)*256 + tid;
        if (wid < 442368) {
          // jax conv_transpose (no flip): ky=0->(py0,dy1); ky=1->(py1,dy0); ky=2->(py0,dy0)
          int c, m, ky, kx; float val;
          if (wid < 294912) {
            c = wid / 1152; int r = wid - c*1152; m = r / 9; int t9 = r - m*9; ky = t9/3; kx = t9 - ky*3;
            val = w_sc[wid];
          } else {
            int i2 = wid - 294912;
            c = i2 / 576; int r = i2 - c*576; m = r / 9; int t9 = r - m*9; ky = t9/3; kx = t9 - ky*3;
            val = w_q[i2] * 0.51007023f;   // log2(e)/sqrt(8) folded
            m += 128;
          }
          int py = (ky==1) ? 1 : 0; int dy = (ky==0) ? 1 : 0;
          int px = (kx==1) ? 1 : 0; int dx = (kx==0) ? 1 : 0;
          int cls = py*2 + px;
          int tt, KP, base;
          if (cls==0){ tt = dy*2+dx; KP=1024; base=0; }
          else if (cls==1){ tt = dy; KP=512; base=196608; }
          else if (cls==2){ tt = dx; KP=512; base=294912; }
          else { tt = 0; KP=256; base=393216; }
          wpt[base + m*KP + tt*256 + c] = f2bf(val);
        } else if (wid < 475136) {
          int i = wid - 442368; int m = i >> 8, c = i & 255;
          float vv = (m < 64) ? w_k[m*256 + c] : w_v[(m-64)*256 + c];
          wkv[m*256 + c] = f2bf(vv);
        } else if (wid < 483328) {
          int i = wid - 475136;
          wo2[i] = f2bf(w_o[i]);
        } else if (wid < 500224) {
          int i = wid - 483328;                // halo zero
          int b = i / 4224; int r = i - b*4224;
          int hp = r >> 5, j = r & 31;
          int p;
          if (hp < 34) p = hp;
          else if (hp < 68) p = 33*34 + (hp - 34);
          else if (hp < 100) p = (hp - 68 + 1)*34;
          else p = (hp - 100 + 1)*34 + 33;
          *(us8*)(xrTp + (((size_t)(b*1156 + p))<<8) + j*8) = (us8)0;
        }
      }
    }
  }
  gbar(bar + 0);

  // ---------------- phase 1: conv-transpose GEMMs + k/v GEMM ----------------
  {
    u16* Blds = (u16*)SM;
    for (int u = bid; u < 923; u += NBLK) {
      if (u < 795) {
        int mb = u % 3, cy = u / 3;
        if (cy < 69)       conv_cls<0,0,4>(xrTp, wpt,          outF, qh, mb, cy,     Blds);
        else if (cy < 135) conv_cls<0,1,2>(xrTp, wpt + 196608, outF, qh, mb, cy-69,  Blds);
        else if (cy < 201) conv_cls<1,0,2>(xrTp, wpt + 294912, outF, qh, mb, cy-135, Blds);
        else               conv_cls<1,1,1>(xrTp, wpt + 393216, outF, qh, mb, cy-201, Blds);
      } else {
        int t = u - 795;
        int mb = t & 1, nb = t >> 1;
        int lane = tid & 63, wv = tid >> 6, quad = lane >> 4, c15 = lane & 15;
        int sn = tid >> 2, sg = tid & 3;
        int n_g = nb*64 + sn;
        int b0 = n_g >> 10, pix0 = n_g & 1023, y0 = pix0 >> 5, x0 = pix0 & 31;
        const u16* bsrc = xrTp + (((size_t)(b0*1156 + (y0+1)*34 + x0+1))<<8) + sg*16;
        f4 acc[4];
        #pragma unroll
        for (int i=0;i<4;i++) acc[i] = (f4){0.f,0.f,0.f,0.f};
        const u16* arow = wkv + (size_t)(mb*64 + wv*16 + c15)*256 + quad*8;
        us8 cv0 = *(const us8*)bsrc, cv1 = *(const us8*)(bsrc + 8);
        int pb = 0;
        for (int kt = 0; kt < 4; ++kt) {
          u16* Bw = Blds + pb*4608;
          *(us8*)(Bw + sn*72 + sg*16) = cv0;
          *(us8*)(Bw + sn*72 + sg*16 + 8) = cv1;
          __syncthreads();
          if (kt < 3) { cv0 = *(const us8*)(bsrc + (kt+1)*64); cv1 = *(const us8*)(bsrc + (kt+1)*64 + 8); }
          s8v a0 = *(const s8v*)(arow + kt*64);
          s8v a1 = *(const s8v*)(arow + kt*64 + 32);
          #pragma unroll
          for (int t4=0;t4<4;t4++) {
            const u16* br = Blds + pb*4608 + (t4*16 + c15)*72 + quad*8;
            s8v bf0 = *(const s8v*)br;
            s8v bf1 = *(const s8v*)(br + 32);
            acc[t4] = __builtin_amdgcn_mfma_f32_16x16x32_bf16(a0, bf0, acc[t4], 0, 0, 0);
            acc[t4] = __builtin_amdgcn_mfma_f32_16x16x32_bf16(a1, bf1, acc[t4], 0, 0, 0);
          }
          pb ^= 1;
        }
        int ml = wv*16 + quad*4;
        #pragma unroll
        for (int t4=0;t4<4;t4++) {
          int n2 = nb*64 + t4*16 + c15;
          int b = n2 >> 10, pix = n2 & 1023;
          if (mb == 0) {
            int h = ml >> 3, d0 = ml & 7;
            u16 pk[4];
            #pragma unroll
            for (int rg=0; rg<4; rg++) pk[rg] = f2h(acc[t4][rg]);
            *(uint2*)(kT + ((size_t)(b*8+h)<<13) + pix*8 + d0) = *(uint2*)pk;
          } else {
            #pragma unroll
            for (int rg=0; rg<4; rg++)
              vbuf[(((size_t)(b*64 + ml + rg))<<10) + pix] = f2h(acc[t4][rg]);
          }
        }
      }
      __syncthreads();
    }
  }
  gbar(bar + 1);

  // ---------------- phase 2: attention (no-max softmax, 2 q-tiles/wave) ----------------
  {
    u16* KL = (u16*)SM;
    u16* VL = KL + 8192;
    int lane = tid & 63, wv = tid >> 6, quad = lane >> 4, c15 = lane & 15;
    for (int u = bid; u < 1088; u += NBLK) {
      int qt = u % 34, bh = u / 34;
      int b = bh >> 3, h = bh & 7;
      {
        const uint4* kg = (const uint4*)(kT + ((size_t)bh << 13));
        for (int i = tid; i < 1024; i += 256) ((uint4*)KL)[i] = kg[i];
        const u16* vg = vbuf + ((size_t)(b*64 + h*8) << 10);
        for (int i = tid; i < 1024; i += 256) {
          int dv = i >> 7, k8 = (i & 127) << 3;
          *(uint4*)(VL + dv*1032 + k8) = *(const uint4*)(vg + (dv<<10) + k8);
        }
        if (tid < 129) {
          us8 ones;
          #pragma unroll
          for (int i=0;i<8;i++) ones[i] = 0x3C00;
          *(us8*)(VL + 8*1032 + tid*8) = ones;
        }
      }
      __syncthreads();
      int q0 = qt*128 + wv*32 + c15;
      int q1 = q0 + 16;
      int qa = q0 < 4224 ? q0 : 4224;
      int qb = q1 < 4224 ? q1 : 4224;
      uint2 t0 = *(const uint2*)(qh + (((size_t)(b*4225 + qa))<<6) + h*8 + (quad&1)*4);
      uint2 t1 = *(const uint2*)(qh + (((size_t)(b*4225 + qb))<<6) + h*8 + (quad&1)*4);
      h4 bq0 = quad < 2 ? *(h4*)&t0 : (h4)(_Float16)0.f;
      h4 bq1 = quad < 2 ? *(h4*)&t1 : (h4)(_Float16)0.f;
      const u16* klb = KL + c15*8 + (quad&1)*4;
      int vr = c15 > 8 ? 8 : c15;
      const u16* vlb = VL + vr*1032 + quad*4;
      const f4 zf = {0.f,0.f,0.f,0.f};
      f4 O0 = {0.f,0.f,0.f,0.f}, O1 = {0.f,0.f,0.f,0.f};
      union HU { uint2 u; h4 h; };
      #pragma unroll 8
      for (int kt=0; kt<64; ++kt) {
        h4 ak = *(const h4*)(klb + kt*128);
        h4 av = *(const h4*)(vlb + kt*16);
        f4 s0 = __builtin_amdgcn_mfma_f32_16x16x16f16(ak, bq0, zf, 0, 0, 0);
        f4 s1 = __builtin_amdgcn_mfma_f32_16x16x16f16(ak, bq1, zf, 0, 0, 0);
        g2 p0l = __builtin_amdgcn_cvt_pkrtz(__builtin_amdgcn_exp2f(s0[0]), __builtin_amdgcn_exp2f(s0[1]));
        g2 p0h = __builtin_amdgcn_cvt_pkrtz(__builtin_amdgcn_exp2f(s0[2]), __builtin_amdgcn_exp2f(s0[3]));
        g2 p1l = __builtin_amdgcn_cvt_pkrtz(__builtin_amdgcn_exp2f(s1[0]), __builtin_amdgcn_exp2f(s1[1]));
        g2 p1h = __builtin_amdgcn_cvt_pkrtz(__builtin_amdgcn_exp2f(s1[2]), __builtin_amdgcn_exp2f(s1[3]));
        HU u0; u0.u.x = __builtin_bit_cast(u32, p0l); u0.u.y = __builtin_bit_cast(u32, p0h);
        HU u1; u1.u.x = __builtin_bit_cast(u32, p1l); u1.u.y = __builtin_bit_cast(u32, p1h);
        O0 = __builtin_amdgcn_mfma_f32_16x16x16f16(av, u0.h, O0, 0, 0, 0);
        O1 = __builtin_amdgcn_mfma_f32_16x16x16f16(av, u1.h, O1, 0, 0, 0);
      }
      float l0 = __shfl(O0[0], 32 + c15, 64);
      float l1 = __shfl(O1[0], 32 + c15, 64);
      float r0 = __builtin_amdgcn_rcpf(l0);
      float r1 = __builtin_amdgcn_rcpf(l1);
      if (quad < 2) {
        if (q0 < 4225) {
          u16 pk[4];
          #pragma unroll
          for (int rg=0;rg<4;rg++) pk[rg] = f2bf(O0[rg]*r0);
          *(uint2*)(attT + (((size_t)(b*4225 + q0))<<6) + h*8 + quad*4) = *(uint2*)pk;
        }
        if (q1 < 4225) {
          u16 pk[4];
          #pragma unroll
          for (int rg=0;rg<4;rg++) pk[rg] = f2bf(O1[rg]*r1);
          *(uint2*)(attT + (((size_t)(b*4225 + q1))<<6) + h*8 + quad*4) = *(uint2*)pk;
        }
      }
      __syncthreads();
    }
  }
  gbar(bar + 2);

  // ---------------- phase 3: output projection + shortcut add ----------------
  {
    int lane = tid & 63, wv = tid >> 6, quad = lane >> 4, c15 = lane & 15;
    for (int u = bid; u < 268; u += NBLK) {
      int nbi = u % 67, b = u / 67;
      f4 acc[2][4];
      #pragma unroll
      for (int am=0;am<2;am++)
        #pragma unroll
        for (int i=0;i<4;i++) acc[am][i] = (f4){0.f,0.f,0.f,0.f};
      #pragma unroll
      for (int kt = 0; kt < 2; ++kt) {
        s8v a0 = *(const s8v*)(wo2 + (size_t)(wv*32 + c15)*64 + kt*32 + quad*8);
        s8v a1 = *(const s8v*)(wo2 + (size_t)(wv*32 + 16 + c15)*64 + kt*32 + quad*8);
        #pragma unroll
        for (int t4=0;t4<4;t4++) {
          int n = nbi*64 + t4*16 + c15;
          int nc = n < 4224 ? n : 4224;
          s8v bf = *(const s8v*)(attT + (((size_t)(b*4225 + nc))<<6) + kt*32 + quad*8);
          acc[0][t4] = __builtin_amdgcn_mfma_f32_16x16x32_bf16(a0, bf, acc[0][t4], 0, 0, 0);
          acc[1][t4] = __builtin_amdgcn_mfma_f32_16x16x32_bf16(a1, bf, acc[1][t4], 0, 0, 0);
        }
      }
      #pragma unroll
      for (int am=0;am<2;am++) {
        int mrow = wv*32 + am*16 + quad*4;
        #pragma unroll
        for (int t4=0;t4<4;t4++) {
          int n2 = nbi*64 + t4*16 + c15;
          if (n2 < 4225) {
            float* op = outF + (size_t)(b*128 + mrow)*4225 + n2;
            #pragma unroll
            for (int rg=0; rg<4; rg++) op[(size_t)rg*4225] += acc[am][t4][rg];
          }
        }
      }
    }
  }
}

extern "C" void kernel_launch(void* const* d_in, const int* in_sizes, int n_in,
                              void* d_out, int out_size, void* d_ws, size_t ws_size,
                              hipStream_t stream) {
  const float* x     = (const float*)d_in[0];
  const float* gamma = (const float*)d_in[1];
  const float* beta  = (const float*)d_in[2];
  const float* mean  = (const float*)d_in[3];
  const float* var   = (const float*)d_in[4];
  const float* w_sc  = (const float*)d_in[5];
  const float* w_q   = (const float*)d_in[6];
  const float* w_k   = (const float*)d_in[7];
  const float* w_v   = (const float*)d_in[8];
  const float* w_o   = (const float*)d_in[9];
  char* ws = (char*)d_ws;
  float* outF = (float*)d_out;

  hipMemsetAsync(ws, 0, 256, stream);   // zero the grid-barrier counters
  k_mega<<<NBLK, 256, 0, stream>>>(x, gamma, beta, mean, var, w_sc, w_q, w_k, w_v, w_o,
                                   ws, outF);
}

// Round 9
// 214.580 us; speedup vs baseline: 2.1656x; 2.1437x over previous
//
#include <hip/hip_runtime.h>

typedef unsigned short u16;
typedef unsigned int u32;

typedef float f4 __attribute__((ext_vector_type(4)));
typedef short s8v __attribute__((ext_vector_type(8)));
typedef u16 us8 __attribute__((ext_vector_type(8)));
typedef _Float16 h4 __attribute__((ext_vector_type(4)));
typedef __fp16 g2 __attribute__((ext_vector_type(2)));

__device__ __forceinline__ u16 f2bf(float x){ u32 b=__float_as_uint(x); b += 0x7FFFu + ((b>>16)&1u); return (u16)(b>>16); }
__device__ __forceinline__ u16 f2h(float x){ union{_Float16 h; u16 u;} c; c.h=(_Float16)x; return c.u; }

// ---- workspace byte offsets (barrier block: bytes 0..4095) ----
#define O_XRT  4096u                     // bf16 xrTp [4][34*34 pix][256 c] (zero halo)
#define O_WPT  (O_XRT + 2367488u)        // bf16 conv A, 4 parity classes [192][Kp]
#define O_QH   (O_WPT + 884736u)         // f16  q (pre-scaled) [4][4225 pix][64 d]
#define O_KT   (O_QH  + 2163200u)        // f16  k [b][h][1024 key][8 d]
#define O_V    (O_KT  + 524288u)         // f16  v [b][64 dv][1024 key]
#define O_ATT  (O_V   + 524288u)         // bf16 attT [4][4225][64 dv]
#define O_WKV  (O_ATT + 2163200u)        // bf16 [128][256]
#define O_WO2  (O_WKV + 65536u)          // bf16 [128][64]

#define NBLK 512

// Striped-arrive + master-release barrier.
// Phase p layout (u32 indices): stripes at p*288 + s*32 (8 stripes, 128B apart),
// release flag at p*288 + 256. Arrive: 1 RMW to own stripe. Block 0 aggregates
// and publishes release; others poll the read-only flag with long s_sleep backoff.
__device__ __forceinline__ void gbar(u32* base, int phase) {
  __syncthreads();
  if (threadIdx.x == 0) {
    u32* st  = base + phase*288;
    u32* rel = st + 256;
    __threadfence();
    atomicAdd(st + (blockIdx.x & 7)*32, 1u);
    if (blockIdx.x == 0) {
      u32 sum;
      do {
        __builtin_amdgcn_s_sleep(2);
        sum = 0;
        #pragma unroll
        for (int s = 0; s < 8; ++s)
          sum += __hip_atomic_load(st + s*32, __ATOMIC_RELAXED, __HIP_MEMORY_SCOPE_AGENT);
      } while (sum < (u32)NBLK);
      __threadfence();
      __hip_atomic_store(rel, 1u, __ATOMIC_RELAXED, __HIP_MEMORY_SCOPE_AGENT);
    } else {
      while (__hip_atomic_load(rel, __ATOMIC_RELAXED, __HIP_MEMORY_SCOPE_AGENT) == 0u)
        __builtin_amdgcn_s_sleep(32);
      __threadfence();
    }
  }
  __syncthreads();
}

// ---------- conv class body (R5-proven: mb-split, padded halo, dbuf 1-barrier) ----------
template<int PY,int PX,int TT>
__device__ __forceinline__ void conv_cls(
    const u16* __restrict__ xrTp, const u16* __restrict__ wcls,
    float* __restrict__ outF, u16* __restrict__ qh,
    int mb, int nb, u16* Blds)
{
  constexpr int Hy = 33 - PY, Wx = 33 - PX;
  constexpr int NC = 4*Hy*Wx;
  constexpr int KP = TT*256;
  constexpr int NKT = KP/64;
  int tid = threadIdx.x;
  int lane = tid & 63, wv = tid >> 6, quad = lane >> 4, c15 = lane & 15;
  int sn = tid >> 2, sg = tid & 3;
  int n_g = nb*64 + sn;
  int ncl = n_g < NC ? n_g : NC-1;
  int bb = ncl/(Hy*Wx); int rem = ncl - bb*(Hy*Wx); int yq = rem/Wx; int xq = rem - yq*Wx;
  const u16* bsrc = xrTp + (((size_t)(bb*1156 + (yq+1)*34 + xq+1))<<8) + sg*16;
  f4 acc[4];
  #pragma unroll
  for (int i=0;i<4;i++) acc[i] = (f4){0.f,0.f,0.f,0.f};
  const u16* arow = wcls + (size_t)(mb*64 + wv*16 + c15)*KP + quad*8;
  auto loadB = [&](int kt, us8& v0, us8& v1) {
    int tt = kt >> 2, c0 = (kt & 3)*64;
    int dy, dx;
    if (TT==4){ dy = tt>>1; dx = tt&1; }
    else if (TT==2){ if (PX==1){ dy=tt; dx=0; } else { dy=0; dx=tt; } }
    else { dy=0; dx=0; }
    const u16* p = bsrc - (((dy*34+dx))<<8) + c0;
    v0 = *(const us8*)p;
    v1 = *(const us8*)(p+8);
  };
  us8 cv0, cv1; loadB(0, cv0, cv1);
  int pb = 0;
  for (int kt = 0; kt < NKT; ++kt) {
    u16* Bw = Blds + pb*4608;
    *(us8*)(Bw + sn*72 + sg*16) = cv0;
    *(us8*)(Bw + sn*72 + sg*16 + 8) = cv1;
    __syncthreads();
    if (kt + 1 < NKT) loadB(kt+1, cv0, cv1);
    s8v a0 = *(const s8v*)(arow + kt*64);
    s8v a1 = *(const s8v*)(arow + kt*64 + 32);
    #pragma unroll
    for (int t4=0;t4<4;t4++) {
      const u16* br = Blds + pb*4608 + (t4*16 + c15)*72 + quad*8;
      s8v bf0 = *(const s8v*)br;
      s8v bf1 = *(const s8v*)(br + 32);
      acc[t4] = __builtin_amdgcn_mfma_f32_16x16x32_bf16(a0, bf0, acc[t4], 0, 0, 0);
      acc[t4] = __builtin_amdgcn_mfma_f32_16x16x32_bf16(a1, bf1, acc[t4], 0, 0, 0);
    }
    pb ^= 1;
  }
  #pragma unroll
  for (int t4=0;t4<4;t4++) {
    int n2 = nb*64 + t4*16 + c15;
    if (n2 < NC) {
      int bb2 = n2/(Hy*Wx); int rem2 = n2 - bb2*(Hy*Wx); int yq2 = rem2/Wx; int xq2 = rem2 - yq2*Wx;
      int pix = (2*yq2 + PY)*65 + (2*xq2 + PX);
      if (mb < 2) {
        int mrow = mb*64 + wv*16 + quad*4;
        #pragma unroll
        for (int rg=0; rg<4; rg++)
          outF[(size_t)(bb2*128 + mrow + rg)*4225 + pix] = acc[t4][rg];
      } else {
        int dv = wv*16 + quad*4;
        u16 pk[4];
        #pragma unroll
        for (int rg=0; rg<4; rg++) pk[rg] = f2h(acc[t4][rg]);
        *(uint2*)(qh + (((size_t)(bb2*4225 + pix))<<6) + dv) = *(uint2*)pk;
      }
    }
  }
}

// =================== mega-kernel: prep | conv+kv | attn | proj ===================
__global__ __launch_bounds__(256, 2) void k_mega(
    const float* __restrict__ x, const float* __restrict__ gamma, const float* __restrict__ beta,
    const float* __restrict__ mean, const float* __restrict__ var,
    const float* __restrict__ w_sc, const float* __restrict__ w_q,
    const float* __restrict__ w_k, const float* __restrict__ w_v, const float* __restrict__ w_o,
    char* __restrict__ ws, float* __restrict__ outF)
{
  __shared__ __align__(16) char SM[35072];
  u32* bar = (u32*)ws;
  u16* xrTp = (u16*)(ws + O_XRT);
  u16* wpt  = (u16*)(ws + O_WPT);
  u16* qh   = (u16*)(ws + O_QH);
  u16* kT   = (u16*)(ws + O_KT);
  u16* vbuf = (u16*)(ws + O_V);
  u16* attT = (u16*)(ws + O_ATT);
  u16* wkv  = (u16*)(ws + O_WKV);
  u16* wo2  = (u16*)(ws + O_WO2);
  int bid = blockIdx.x, tid = threadIdx.x;

  // ---------------- phase 0: BN+ReLU transpose (padded) + weight re-layouts ----------------
  {
    float* SS = (float*)SM; float* SH = SS + 64; u16* T = (u16*)(SH + 64);
    for (int u = bid; u < 2466; u += NBLK) {
      if (u < 512) {
        int b = u >> 7, pt = (u >> 2) & 31, ch = u & 3;
        int pix0 = pt*32, c0 = ch*64;
        if (tid < 64) {
          int c = c0 + tid;
          float s = gamma[c]*rsqrtf(var[c] + 1e-5f);
          SS[tid] = s; SH[tid] = beta[c] - mean[c]*s;
        }
        __syncthreads();
        int pix_l = tid & 31, c_l = tid >> 5;
        #pragma unroll
        for (int it = 0; it < 8; ++it) {
          int cl = it*8 + c_l;
          float v = x[(((size_t)(b*256 + c0 + cl))<<10) + pix0 + pix_l];
          T[pix_l*72 + cl] = f2bf(fmaxf(v*SS[cl] + SH[cl], 0.f));
        }
        __syncthreads();
        int pix_r = tid >> 3, j = tid & 7;
        us8 v0 = *(const us8*)(T + pix_r*72 + j*8);
        u16* dst = xrTp + (((size_t)(b*1156 + (pt+1)*34 + 1 + pix_r))<<8) + c0;
        *(us8*)(dst + j*8) = v0;
        __syncthreads();
      } else {
        int wid = (u - 512)*256 + tid;
        if (wid < 442368) {
          // jax conv_transpose (no flip): ky=0->(py0,dy1); ky=1->(py1,dy0); ky=2->(py0,dy0)
          int c, m, ky, kx; float val;
          if (wid < 294912) {
            c = wid / 1152; int r = wid - c*1152; m = r / 9; int t9 = r - m*9; ky = t9/3; kx = t9 - ky*3;
            val = w_sc[wid];
          } else {
            int i2 = wid - 294912;
            c = i2 / 576; int r = i2 - c*576; m = r / 9; int t9 = r - m*9; ky = t9/3; kx = t9 - ky*3;
            val = w_q[i2] * 0.51007023f;   // log2(e)/sqrt(8) folded
            m += 128;
          }
          int py = (ky==1) ? 1 : 0; int dy = (ky==0) ? 1 : 0;
          int px = (kx==1) ? 1 : 0; int dx = (kx==0) ? 1 : 0;
          int cls = py*2 + px;
          int tt, KP, base;
          if (cls==0){ tt = dy*2+dx; KP=1024; base=0; }
          else if (cls==1){ tt = dy; KP=512; base=196608; }
          else if (cls==2){ tt = dx; KP=512; base=294912; }
          else { tt = 0; KP=256; base=393216; }
          wpt[base + m*KP + tt*256 + c] = f2bf(val);
        } else if (wid < 475136) {
          int i = wid - 442368; int m = i >> 8, c = i & 255;
          float vv = (m < 64) ? w_k[m*256 + c] : w_v[(m-64)*256 + c];
          wkv[m*256 + c] = f2bf(vv);
        } else if (wid < 483328) {
          int i = wid - 475136;
          wo2[i] = f2bf(w_o[i]);
        } else if (wid < 500224) {
          int i = wid - 483328;                // halo zero
          int b = i / 4224; int r = i - b*4224;
          int hp = r >> 5, j = r & 31;
          int p;
          if (hp < 34) p = hp;
          else if (hp < 68) p = 33*34 + (hp - 34);
          else if (hp < 100) p = (hp - 68 + 1)*34;
          else p = (hp - 100 + 1)*34 + 33;
          *(us8*)(xrTp + (((size_t)(b*1156 + p))<<8) + j*8) = (us8)0;
        }
      }
    }
  }
  gbar(bar, 0);

  // ---------------- phase 1: conv-transpose GEMMs + k/v GEMM ----------------
  {
    u16* Blds = (u16*)SM;
    for (int u = bid; u < 923; u += NBLK) {
      if (u < 795) {
        int mb = u % 3, cy = u / 3;
        if (cy < 69)       conv_cls<0,0,4>(xrTp, wpt,          outF, qh, mb, cy,     Blds);
        else if (cy < 135) conv_cls<0,1,2>(xrTp, wpt + 196608, outF, qh, mb, cy-69,  Blds);
        else if (cy < 201) conv_cls<1,0,2>(xrTp, wpt + 294912, outF, qh, mb, cy-135, Blds);
        else               conv_cls<1,1,1>(xrTp, wpt + 393216, outF, qh, mb, cy-201, Blds);
      } else {
        int t = u - 795;
        int mb = t & 1, nb = t >> 1;
        int lane = tid & 63, wv = tid >> 6, quad = lane >> 4, c15 = lane & 15;
        int sn = tid >> 2, sg = tid & 3;
        int n_g = nb*64 + sn;
        int b0 = n_g >> 10, pix0 = n_g & 1023, y0 = pix0 >> 5, x0 = pix0 & 31;
        const u16* bsrc = xrTp + (((size_t)(b0*1156 + (y0+1)*34 + x0+1))<<8) + sg*16;
        f4 acc[4];
        #pragma unroll
        for (int i=0;i<4;i++) acc[i] = (f4){0.f,0.f,0.f,0.f};
        const u16* arow = wkv + (size_t)(mb*64 + wv*16 + c15)*256 + quad*8;
        us8 cv0 = *(const us8*)bsrc, cv1 = *(const us8*)(bsrc + 8);
        int pb = 0;
        for (int kt = 0; kt < 4; ++kt) {
          u16* Bw = Blds + pb*4608;
          *(us8*)(Bw + sn*72 + sg*16) = cv0;
          *(us8*)(Bw + sn*72 + sg*16 + 8) = cv1;
          __syncthreads();
          if (kt < 3) { cv0 = *(const us8*)(bsrc + (kt+1)*64); cv1 = *(const us8*)(bsrc + (kt+1)*64 + 8); }
          s8v a0 = *(const s8v*)(arow + kt*64);
          s8v a1 = *(const s8v*)(arow + kt*64 + 32);
          #pragma unroll
          for (int t4=0;t4<4;t4++) {
            const u16* br = Blds + pb*4608 + (t4*16 + c15)*72 + quad*8;
            s8v bf0 = *(const s8v*)br;
            s8v bf1 = *(const s8v*)(br + 32);
            acc[t4] = __builtin_amdgcn_mfma_f32_16x16x32_bf16(a0, bf0, acc[t4], 0, 0, 0);
            acc[t4] = __builtin_amdgcn_mfma_f32_16x16x32_bf16(a1, bf1, acc[t4], 0, 0, 0);
          }
          pb ^= 1;
        }
        int ml = wv*16 + quad*4;
        #pragma unroll
        for (int t4=0;t4<4;t4++) {
          int n2 = nb*64 + t4*16 + c15;
          int b = n2 >> 10, pix = n2 & 1023;
          if (mb == 0) {
            int h = ml >> 3, d0 = ml & 7;
            u16 pk[4];
            #pragma unroll
            for (int rg=0; rg<4; rg++) pk[rg] = f2h(acc[t4][rg]);
            *(uint2*)(kT + ((size_t)(b*8+h)<<13) + pix*8 + d0) = *(uint2*)pk;
          } else {
            #pragma unroll
            for (int rg=0; rg<4; rg++)
              vbuf[(((size_t)(b*64 + ml + rg))<<10) + pix] = f2h(acc[t4][rg]);
          }
        }
      }
      __syncthreads();
    }
  }
  gbar(bar, 1);

  // ---------------- phase 2: attention (no-max softmax, 2 q-tiles/wave) ----------------
  {
    u16* KL = (u16*)SM;
    u16* VL = KL + 8192;
    int lane = tid & 63, wv = tid >> 6, quad = lane >> 4, c15 = lane & 15;
    for (int u = bid; u < 1088; u += NBLK) {
      int qt = u % 34, bh = u / 34;
      int b = bh >> 3, h = bh & 7;
      {
        const uint4* kg = (const uint4*)(kT + ((size_t)bh << 13));
        for (int i = tid; i < 1024; i += 256) ((uint4*)KL)[i] = kg[i];
        const u16* vg = vbuf + ((size_t)(b*64 + h*8) << 10);
        for (int i = tid; i < 1024; i += 256) {
          int dv = i >> 7, k8 = (i & 127) << 3;
          *(uint4*)(VL + dv*1032 + k8) = *(const uint4*)(vg + (dv<<10) + k8);
        }
        if (tid < 129) {
          us8 ones;
          #pragma unroll
          for (int i=0;i<8;i++) ones[i] = 0x3C00;
          *(us8*)(VL + 8*1032 + tid*8) = ones;
        }
      }
      __syncthreads();
      int q0 = qt*128 + wv*32 + c15;
      int q1 = q0 + 16;
      int qa = q0 < 4224 ? q0 : 4224;
      int qb = q1 < 4224 ? q1 : 4224;
      uint2 t0 = *(const uint2*)(qh + (((size_t)(b*4225 + qa))<<6) + h*8 + (quad&1)*4);
      uint2 t1 = *(const uint2*)(qh + (((size_t)(b*4225 + qb))<<6) + h*8 + (quad&1)*4);
      h4 bq0 = quad < 2 ? *(h4*)&t0 : (h4)(_Float16)0.f;
      h4 bq1 = quad < 2 ? *(h4*)&t1 : (h4)(_Float16)0.f;
      const u16* klb = KL + c15*8 + (quad&1)*4;
      int vr = c15 > 8 ? 8 : c15;
      const u16* vlb = VL + vr*1032 + quad*4;
      const f4 zf = {0.f,0.f,0.f,0.f};
      f4 O0 = {0.f,0.f,0.f,0.f}, O1 = {0.f,0.f,0.f,0.f};
      union HU { uint2 u; h4 h; };
      #pragma unroll 8
      for (int kt=0; kt<64; ++kt) {
        h4 ak = *(const h4*)(klb + kt*128);
        h4 av = *(const h4*)(vlb + kt*16);
        f4 s0 = __builtin_amdgcn_mfma_f32_16x16x16f16(ak, bq0, zf, 0, 0, 0);
        f4 s1 = __builtin_amdgcn_mfma_f32_16x16x16f16(ak, bq1, zf, 0, 0, 0);
        g2 p0l = __builtin_amdgcn_cvt_pkrtz(__builtin_amdgcn_exp2f(s0[0]), __builtin_amdgcn_exp2f(s0[1]));
        g2 p0h = __builtin_amdgcn_cvt_pkrtz(__builtin_amdgcn_exp2f(s0[2]), __builtin_amdgcn_exp2f(s0[3]));
        g2 p1l = __builtin_amdgcn_cvt_pkrtz(__builtin_amdgcn_exp2f(s1[0]), __builtin_amdgcn_exp2f(s1[1]));
        g2 p1h = __builtin_amdgcn_cvt_pkrtz(__builtin_amdgcn_exp2f(s1[2]), __builtin_amdgcn_exp2f(s1[3]));
        HU u0; u0.u.x = __builtin_bit_cast(u32, p0l); u0.u.y = __builtin_bit_cast(u32, p0h);
        HU u1; u1.u.x = __builtin_bit_cast(u32, p1l); u1.u.y = __builtin_bit_cast(u32, p1h);
        O0 = __builtin_amdgcn_mfma_f32_16x16x16f16(av, u0.h, O0, 0, 0, 0);
        O1 = __builtin_amdgcn_mfma_f32_16x16x16f16(av, u1.h, O1, 0, 0, 0);
      }
      float l0 = __shfl(O0[0], 32 + c15, 64);
      float l1 = __shfl(O1[0], 32 + c15, 64);
      float r0 = __builtin_amdgcn_rcpf(l0);
      float r1 = __builtin_amdgcn_rcpf(l1);
      if (quad < 2) {
        if (q0 < 4225) {
          u16 pk[4];
          #pragma unroll
          for (int rg=0;rg<4;rg++) pk[rg] = f2bf(O0[rg]*r0);
          *(uint2*)(attT + (((size_t)(b*4225 + q0))<<6) + h*8 + quad*4) = *(uint2*)pk;
        }
        if (q1 < 4225) {
          u16 pk[4];
          #pragma unroll
          for (int rg=0;rg<4;rg++) pk[rg] = f2bf(O1[rg]*r1);
          *(uint2*)(attT + (((size_t)(b*4225 + q1))<<6) + h*8 + quad*4) = *(uint2*)pk;
        }
      }
      __syncthreads();
    }
  }
  gbar(bar, 2);

  // ---------------- phase 3: output projection + shortcut add ----------------
  {
    int lane = tid & 63, wv = tid >> 6, quad = lane >> 4, c15 = lane & 15;
    for (int u = bid; u < 268; u += NBLK) {
      int nbi = u % 67, b = u / 67;
      f4 acc[2][4];
      #pragma unroll
      for (int am=0;am<2;am++)
        #pragma unroll
        for (int i=0;i<4;i++) acc[am][i] = (f4){0.f,0.f,0.f,0.f};
      #pragma unroll
      for (int kt = 0; kt < 2; ++kt) {
        s8v a0 = *(const s8v*)(wo2 + (size_t)(wv*32 + c15)*64 + kt*32 + quad*8);
        s8v a1 = *(const s8v*)(wo2 + (size_t)(wv*32 + 16 + c15)*64 + kt*32 + quad*8);
        #pragma unroll
        for (int t4=0;t4<4;t4++) {
          int n = nbi*64 + t4*16 + c15;
          int nc = n < 4224 ? n : 4224;
          s8v bf = *(const s8v*)(attT + (((size_t)(b*4225 + nc))<<6) + kt*32 + quad*8);
          acc[0][t4] = __builtin_amdgcn_mfma_f32_16x16x32_bf16(a0, bf, acc[0][t4], 0, 0, 0);
          acc[1][t4] = __builtin_amdgcn_mfma_f32_16x16x32_bf16(a1, bf, acc[1][t4], 0, 0, 0);
        }
      }
      #pragma unroll
      for (int am=0;am<2;am++) {
        int mrow = wv*32 + am*16 + quad*4;
        #pragma unroll
        for (int t4=0;t4<4;t4++) {
          int n2 = nbi*64 + t4*16 + c15;
          if (n2 < 4225) {
            float* op = outF + (size_t)(b*128 + mrow)*4225 + n2;
            #pragma unroll
            for (int rg=0; rg<4; rg++) op[(size_t)rg*4225] += acc[am][t4][rg];
          }
        }
      }
    }
  }
}

extern "C" void kernel_launch(void* const* d_in, const int* in_sizes, int n_in,
                              void* d_out, int out_size, void* d_ws, size_t ws_size,
                              hipStream_t stream) {
  const float* x     = (const float*)d_in[0];
  const float* gamma = (const float*)d_in[1];
  const float* beta  = (const float*)d_in[2];
  const float* mean  = (const float*)d_in[3];
  const float* var   = (const float*)d_in[4];
  const float* w_sc  = (const float*)d_in[5];
  const float* w_q   = (const float*)d_in[6];
  const float* w_k   = (const float*)d_in[7];
  const float* w_v   = (const float*)d_in[8];
  const float* w_o   = (const float*)d_in[9];
  char* ws = (char*)d_ws;
  float* outF = (float*)d_out;

  hipMemsetAsync(ws, 0, 4096, stream);   // zero the barrier stripes + release flags
  k_mega<<<NBLK, 256, 0, stream>>>(x, gamma, beta, mean, var, w_sc, w_q, w_k, w_v, w_o,
                                   ws, outF);
}

// Round 10
// 140.920 us; speedup vs baseline: 3.2976x; 1.5227x over previous
//
#include <hip/hip_runtime.h>

typedef unsigned short u16;
typedef unsigned int u32;

typedef float f4 __attribute__((ext_vector_type(4)));
typedef float f16v __attribute__((ext_vector_type(16)));
typedef short s8v __attribute__((ext_vector_type(8)));
typedef u16 us8 __attribute__((ext_vector_type(8)));
typedef _Float16 h4 __attribute__((ext_vector_type(4)));
typedef __fp16 g2 __attribute__((ext_vector_type(2)));

__device__ __forceinline__ u16 f2bf(float x){ u32 b=__float_as_uint(x); b += 0x7FFFu + ((b>>16)&1u); return (u16)(b>>16); }
__device__ __forceinline__ u16 f2h(float x){ union{_Float16 h; u16 u;} c; c.h=(_Float16)x; return c.u; }

// ---- workspace byte offsets ----
#define O_XRT  4096u                     // bf16 xrTp [4][34*34 pix][256 c] (zero halo)
#define O_WPT  (O_XRT + 2367488u)        // bf16 conv A, 4 parity classes [192][Kp]
#define O_QH   (O_WPT + 884736u)         // f16  q (pre-scaled) [4][4225 pix][64 d]
#define O_KT   (O_QH  + 2163200u)        // f16  k [b][h][1024 key][8 d]
#define O_V    (O_KT  + 524288u)         // f16  v [b][64 dv][1024 key]
#define O_ATT  (O_V   + 524288u)         // bf16 attT [4][4225][64 dv]
#define O_WKV  (O_ATT + 2163200u)        // bf16 [128][256]  (w_k rows 0-63, w_v rows 64-127)
#define O_WO2  (O_WKV + 65536u)          // bf16 [128][64]   (w_o direct cast)

// =================== K1: BN+ReLU transpose (padded) + weight re-layouts ===================
__global__ __launch_bounds__(256) void k_prep(
    const float* __restrict__ x, const float* __restrict__ gamma, const float* __restrict__ beta,
    const float* __restrict__ mean, const float* __restrict__ var,
    const float* __restrict__ w_sc, const float* __restrict__ w_q,
    const float* __restrict__ w_k, const float* __restrict__ w_v, const float* __restrict__ w_o,
    u16* __restrict__ xrTp, u16* __restrict__ wpt,
    u16* __restrict__ wkv, u16* __restrict__ wo2)
{
  __shared__ float SS[64], SH[64];
  __shared__ __align__(16) u16 T[32*72];
  int bi = blockIdx.x, tid = threadIdx.x;
  if (bi < 512) {                       // BN+ReLU -> xrTp [pad pix][c], tile 32 pix x 64 c
    int b = bi >> 7, pt = (bi >> 2) & 31, ch = bi & 3;
    int pix0 = pt*32, c0 = ch*64;
    if (tid < 64) {
      int c = c0 + tid;
      float s = gamma[c]*rsqrtf(var[c] + 1e-5f);
      SS[tid] = s; SH[tid] = beta[c] - mean[c]*s;
    }
    __syncthreads();
    int pix_l = tid & 31, c_l = tid >> 5;
    #pragma unroll
    for (int it = 0; it < 8; ++it) {
      int cl = it*8 + c_l;
      float v = x[(((size_t)(b*256 + c0 + cl))<<10) + pix0 + pix_l];
      T[pix_l*72 + cl] = f2bf(fmaxf(v*SS[cl] + SH[cl], 0.f));
    }
    __syncthreads();
    int pix_r = tid >> 3, j = tid & 7;
    us8 v0 = *(const us8*)(T + pix_r*72 + j*8);
    u16* dst = xrTp + (((size_t)(b*1156 + (pt+1)*34 + 1 + pix_r))<<8) + c0;
    *(us8*)(dst + j*8) = v0;
    return;
  }
  int wid = (bi - 512)*256 + tid;
  if (wid < 442368) {
    // jax conv_transpose (no flip): ky=0 -> (py=0,dy=1); ky=1 -> (py=1,dy=0); ky=2 -> (py=0,dy=0)
    int c, m, ky, kx; float val;
    if (wid < 294912) {
      c = wid / 1152; int r = wid - c*1152; m = r / 9; int t9 = r - m*9; ky = t9/3; kx = t9 - ky*3;
      val = w_sc[wid];
    } else {
      int i2 = wid - 294912;
      c = i2 / 576; int r = i2 - c*576; m = r / 9; int t9 = r - m*9; ky = t9/3; kx = t9 - ky*3;
      val = w_q[i2] * 0.51007023f;   // log2(e)/sqrt(8) folded into q weights
      m += 128;
    }
    int py = (ky==1) ? 1 : 0; int dy = (ky==0) ? 1 : 0;
    int px = (kx==1) ? 1 : 0; int dx = (kx==0) ? 1 : 0;
    int cls = py*2 + px;
    int tt, KP, base;
    if (cls==0){ tt = dy*2+dx; KP=1024; base=0; }
    else if (cls==1){ tt = dy; KP=512; base=196608; }
    else if (cls==2){ tt = dx; KP=512; base=294912; }
    else { tt = 0; KP=256; base=393216; }
    wpt[base + m*KP + tt*256 + c] = f2bf(val);
  } else if (wid < 475136) {
    int i = wid - 442368; int m = i >> 8, c = i & 255;
    float vv = (m < 64) ? w_k[m*256 + c] : w_v[(m-64)*256 + c];
    wkv[m*256 + c] = f2bf(vv);
  } else if (wid < 483328) {
    int i = wid - 475136;
    wo2[i] = f2bf(w_o[i]);
  } else if (wid < 500224) {
    int i = wid - 483328;                // halo zero: 4 b x 132 pix x 32 us8
    int b = i / 4224; int r = i - b*4224;
    int hp = r >> 5, j = r & 31;
    int p;
    if (hp < 34) p = hp;
    else if (hp < 68) p = 33*34 + (hp - 34);
    else if (hp < 100) p = (hp - 68 + 1)*34;
    else p = (hp - 100 + 1)*34 + 33;
    *(us8*)(xrTp + (((size_t)(b*1156 + p))<<8) + j*8) = (us8)0;
  }
}

// =================== K2: conv-transpose GEMM + k/v GEMM (32x32x16 MFMA) ===================
// Wave tiling: 4 waves = 2 M-tiles x 2 N-tiles of 32. One 32x32 acc per wave.
// A lane layout: m = lane&31, k = (lane>>5)*8 + j. B: n = lane&31, same k-half.
// C/D: col = lane&31, row = (reg&3) + 8*(reg>>2) + 4*(lane>>5).
template<int PY,int PX,int TT>
__device__ __forceinline__ void conv_cls(
    const u16* __restrict__ xrTp, const u16* __restrict__ wcls,
    float* __restrict__ outF, u16* __restrict__ qh,
    int mb, int nb, u16* Blds)
{
  constexpr int Hy = 33 - PY, Wx = 33 - PX;
  constexpr int NC = 4*Hy*Wx;
  constexpr int KP = TT*256;
  constexpr int NKT = KP/64;
  int tid = threadIdx.x;
  int lane = tid & 63, wv = tid >> 6;
  int tm = wv & 1, tn = wv >> 1;
  int n32 = lane & 31, kh = lane >> 5;
  int sn = tid >> 2, sg = tid & 3;
  int n_g = nb*64 + sn;
  int ncl = n_g < NC ? n_g : NC-1;
  int bb = ncl/(Hy*Wx); int rem = ncl - bb*(Hy*Wx); int yq = rem/Wx; int xq = rem - yq*Wx;
  const u16* bsrc = xrTp + (((size_t)(bb*1156 + (yq+1)*34 + xq+1))<<8) + sg*16;
  f16v acc = (f16v)0.f;
  const u16* arow = wcls + (size_t)(mb*64 + tm*32 + n32)*KP + kh*8;
  auto loadB = [&](int kt, us8& v0, us8& v1) {
    int tt = kt >> 2, c0 = (kt & 3)*64;
    int dy, dx;
    if (TT==4){ dy = tt>>1; dx = tt&1; }
    else if (TT==2){ if (PX==1){ dy=tt; dx=0; } else { dy=0; dx=tt; } }
    else { dy=0; dx=0; }
    const u16* p = bsrc - (((dy*34+dx))<<8) + c0;
    v0 = *(const us8*)p;
    v1 = *(const us8*)(p+8);
  };
  us8 cv0, cv1; loadB(0, cv0, cv1);
  s8v a[4], an[4];
  #pragma unroll
  for (int s=0;s<4;s++) a[s] = *(const s8v*)(arow + s*16);
  int pb = 0;
  for (int kt = 0; kt < NKT; ++kt) {
    u16* Bw = Blds + pb*4608;
    *(us8*)(Bw + sn*72 + sg*16) = cv0;
    *(us8*)(Bw + sn*72 + sg*16 + 8) = cv1;
    __syncthreads();
    if (kt + 1 < NKT) {
      loadB(kt+1, cv0, cv1);
      #pragma unroll
      for (int s=0;s<4;s++) an[s] = *(const s8v*)(arow + (kt+1)*64 + s*16);
    }
    const u16* br = Blds + pb*4608 + (tn*32 + n32)*72 + kh*8;
    #pragma unroll
    for (int s=0;s<4;s++) {
      s8v bf = *(const s8v*)(br + s*16);
      acc = __builtin_amdgcn_mfma_f32_32x32x16_bf16(a[s], bf, acc, 0, 0, 0);
    }
    #pragma unroll
    for (int s=0;s<4;s++) a[s] = an[s];
    pb ^= 1;
  }
  int n2 = nb*64 + tn*32 + n32;
  if (n2 < NC) {
    int bb2 = n2/(Hy*Wx); int rem2 = n2 - bb2*(Hy*Wx); int yq2 = rem2/Wx; int xq2 = rem2 - yq2*Wx;
    int pix = (2*yq2 + PY)*65 + (2*xq2 + PX);
    if (mb < 2) {
      #pragma unroll
      for (int g=0; g<4; g++) {
        int m0 = mb*64 + tm*32 + g*8 + kh*4;
        #pragma unroll
        for (int r=0;r<4;r++)
          outF[(size_t)(bb2*128 + m0 + r)*4225 + pix] = acc[g*4+r];
      }
    } else {
      #pragma unroll
      for (int g=0; g<4; g++) {
        int dv = tm*32 + g*8 + kh*4;
        u16 pk[4];
        #pragma unroll
        for (int r=0;r<4;r++) pk[r] = f2h(acc[g*4+r]);
        *(uint2*)(qh + (((size_t)(bb2*4225 + pix))<<6) + dv) = *(uint2*)pk;
      }
    }
  }
}

__global__ __launch_bounds__(256) void k_conv(
    const u16* __restrict__ xrTp, const u16* __restrict__ wpt, const u16* __restrict__ wkv,
    float* __restrict__ outF, u16* __restrict__ qh,
    u16* __restrict__ kT, u16* __restrict__ vbuf)
{
  __shared__ __align__(16) u16 Blds[2*4608];
  int bi = blockIdx.x;
  if (bi < 795) {
    int mb = bi % 3, cy = bi / 3;
    if (cy < 69)       conv_cls<0,0,4>(xrTp, wpt,          outF, qh, mb, cy,     Blds);
    else if (cy < 135) conv_cls<0,1,2>(xrTp, wpt + 196608, outF, qh, mb, cy-69,  Blds);
    else if (cy < 201) conv_cls<1,0,2>(xrTp, wpt + 294912, outF, qh, mb, cy-135, Blds);
    else               conv_cls<1,1,1>(xrTp, wpt + 393216, outF, qh, mb, cy-201, Blds);
    return;
  }
  // k/v GEMM: [64 m per block, mb=0 k / mb=1 v] x [256 c] x [4096 n], 32x32 tiles
  int t = bi - 795;
  int mb = t & 1, nbk = t >> 1;
  int tid = threadIdx.x;
  int lane = tid & 63, wv = tid >> 6;
  int tm = wv & 1, tn = wv >> 1;
  int n32 = lane & 31, kh = lane >> 5;
  int sn = tid >> 2, sg = tid & 3;
  int n_g = nbk*64 + sn;
  int b0 = n_g >> 10, pix0 = n_g & 1023, y0 = pix0 >> 5, x0 = pix0 & 31;
  const u16* bsrc = xrTp + (((size_t)(b0*1156 + (y0+1)*34 + x0+1))<<8) + sg*16;
  f16v acc = (f16v)0.f;
  const u16* arow = wkv + (size_t)(mb*64 + tm*32 + n32)*256 + kh*8;
  us8 cv0 = *(const us8*)bsrc, cv1 = *(const us8*)(bsrc + 8);
  s8v a[4], an[4];
  #pragma unroll
  for (int s=0;s<4;s++) a[s] = *(const s8v*)(arow + s*16);
  int pb = 0;
  for (int kt = 0; kt < 4; ++kt) {
    u16* Bw = Blds + pb*4608;
    *(us8*)(Bw + sn*72 + sg*16) = cv0;
    *(us8*)(Bw + sn*72 + sg*16 + 8) = cv1;
    __syncthreads();
    if (kt < 3) {
      cv0 = *(const us8*)(bsrc + (kt+1)*64); cv1 = *(const us8*)(bsrc + (kt+1)*64 + 8);
      #pragma unroll
      for (int s=0;s<4;s++) an[s] = *(const s8v*)(arow + (kt+1)*64 + s*16);
    }
    const u16* br = Blds + pb*4608 + (tn*32 + n32)*72 + kh*8;
    #pragma unroll
    for (int s=0;s<4;s++) {
      s8v bf = *(const s8v*)(br + s*16);
      acc = __builtin_amdgcn_mfma_f32_32x32x16_bf16(a[s], bf, acc, 0, 0, 0);
    }
    #pragma unroll
    for (int s=0;s<4;s++) a[s] = an[s];
    pb ^= 1;
  }
  int n2 = nbk*64 + tn*32 + n32;
  int b = n2 >> 10, pix = n2 & 1023;
  #pragma unroll
  for (int g=0; g<4; g++) {
    int ml = tm*32 + g*8 + kh*4;
    if (mb == 0) {                      // k rows: kT [b][h][key][8 d], d0 in {0,4}
      int h = ml >> 3, d0 = ml & 7;
      u16 pk[4];
      #pragma unroll
      for (int r=0; r<4; r++) pk[r] = f2h(acc[g*4+r]);
      *(uint2*)(kT + ((size_t)(b*8+h)<<13) + pix*8 + d0) = *(uint2*)pk;
    } else {                            // v rows: vbuf [b][dv][key]
      #pragma unroll
      for (int r=0; r<4; r++)
        vbuf[(((size_t)(b*64 + ml + r))<<10) + pix] = f2h(acc[g*4+r]);
    }
  }
}

// =================== K3: attention (no-max softmax, 1 pass) ===================
__global__ __launch_bounds__(256) void k_attn(
    const u16* __restrict__ qh, const u16* __restrict__ kT, const u16* __restrict__ vbuf,
    u16* __restrict__ attT)
{
  __shared__ __align__(16) u16 KL[8192];
  __shared__ __align__(16) u16 VL[9*1032];
  int qt = blockIdx.x, bh = blockIdx.y;
  int b = bh >> 3, h = bh & 7;
  int tid = threadIdx.x, lane = tid & 63, wv = tid >> 6, quad = lane >> 4, c15 = lane & 15;
  {
    const uint4* kg = (const uint4*)(kT + ((size_t)bh << 13));
    for (int i = tid; i < 1024; i += 256) ((uint4*)KL)[i] = kg[i];
    const u16* vg = vbuf + ((size_t)(b*64 + h*8) << 10);
    for (int i = tid; i < 1024; i += 256) {
      int dv = i >> 7, k8 = (i & 127) << 3;
      *(uint4*)(VL + dv*1032 + k8) = *(const uint4*)(vg + (dv<<10) + k8);
    }
    if (tid < 129) {
      us8 ones;
      #pragma unroll
      for (int i=0;i<8;i++) ones[i] = 0x3C00;
      *(us8*)(VL + 8*1032 + tid*8) = ones;
    }
  }
  __syncthreads();
  int q0 = qt*128 + wv*32 + c15;
  int q1 = q0 + 16;
  int qa = q0 < 4224 ? q0 : 4224;
  int qb = q1 < 4224 ? q1 : 4224;
  uint2 t0 = *(const uint2*)(qh + (((size_t)(b*4225 + qa))<<6) + h*8 + (quad&1)*4);
  uint2 t1 = *(const uint2*)(qh + (((size_t)(b*4225 + qb))<<6) + h*8 + (quad&1)*4);
  h4 bq0 = quad < 2 ? *(h4*)&t0 : (h4)(_Float16)0.f;
  h4 bq1 = quad < 2 ? *(h4*)&t1 : (h4)(_Float16)0.f;
  const u16* klb = KL + c15*8 + (quad&1)*4;
  int vr = c15 > 8 ? 8 : c15;
  const u16* vlb = VL + vr*1032 + quad*4;
  const f4 zf = {0.f,0.f,0.f,0.f};
  f4 O0 = {0.f,0.f,0.f,0.f}, O1 = {0.f,0.f,0.f,0.f};
  union HU { uint2 u; h4 h; };
  #pragma unroll 8
  for (int kt=0; kt<64; ++kt) {
    h4 ak = *(const h4*)(klb + kt*128);
    h4 av = *(const h4*)(vlb + kt*16);
    f4 s0 = __builtin_amdgcn_mfma_f32_16x16x16f16(ak, bq0, zf, 0, 0, 0);
    f4 s1 = __builtin_amdgcn_mfma_f32_16x16x16f16(ak, bq1, zf, 0, 0, 0);
    g2 p0l = __builtin_amdgcn_cvt_pkrtz(__builtin_amdgcn_exp2f(s0[0]), __builtin_amdgcn_exp2f(s0[1]));
    g2 p0h = __builtin_amdgcn_cvt_pkrtz(__builtin_amdgcn_exp2f(s0[2]), __builtin_amdgcn_exp2f(s0[3]));
    g2 p1l = __builtin_amdgcn_cvt_pkrtz(__builtin_amdgcn_exp2f(s1[0]), __builtin_amdgcn_exp2f(s1[1]));
    g2 p1h = __builtin_amdgcn_cvt_pkrtz(__builtin_amdgcn_exp2f(s1[2]), __builtin_amdgcn_exp2f(s1[3]));
    HU u0; u0.u.x = __builtin_bit_cast(u32, p0l); u0.u.y = __builtin_bit_cast(u32, p0h);
    HU u1; u1.u.x = __builtin_bit_cast(u32, p1l); u1.u.y = __builtin_bit_cast(u32, p1h);
    O0 = __builtin_amdgcn_mfma_f32_16x16x16f16(av, u0.h, O0, 0, 0, 0);
    O1 = __builtin_amdgcn_mfma_f32_16x16x16f16(av, u1.h, O1, 0, 0, 0);
  }
  float l0 = __shfl(O0[0], 32 + c15, 64);
  float l1 = __shfl(O1[0], 32 + c15, 64);
  float r0 = __builtin_amdgcn_rcpf(l0);
  float r1 = __builtin_amdgcn_rcpf(l1);
  if (quad < 2) {
    if (q0 < 4225) {
      u16 pk[4];
      #pragma unroll
      for (int rg=0;rg<4;rg++) pk[rg] = f2bf(O0[rg]*r0);
      *(uint2*)(attT + (((size_t)(b*4225 + q0))<<6) + h*8 + quad*4) = *(uint2*)pk;
    }
    if (q1 < 4225) {
      u16 pk[4];
      #pragma unroll
      for (int rg=0;rg<4;rg++) pk[rg] = f2bf(O1[rg]*r1);
      *(uint2*)(attT + (((size_t)(b*4225 + q1))<<6) + h*8 + quad*4) = *(uint2*)pk;
    }
  }
}

// =================== K4: output projection GEMM (no LDS, mb-split) + shortcut add ===================
__global__ __launch_bounds__(256) void k_proj(
    const u16* __restrict__ attT, const u16* __restrict__ wo2, float* __restrict__ outF)
{
  int nbi = blockIdx.x, mb = blockIdx.y, b = blockIdx.z;
  int tid = threadIdx.x;
  int lane = tid & 63, wv = tid >> 6, quad = lane >> 4, c15 = lane & 15;
  f4 acc[4];
  #pragma unroll
  for (int i=0;i<4;i++) acc[i] = (f4){0.f,0.f,0.f,0.f};
  #pragma unroll
  for (int kt = 0; kt < 2; ++kt) {
    s8v a0 = *(const s8v*)(wo2 + (size_t)(mb*64 + wv*16 + c15)*64 + kt*32 + quad*8);
    #pragma unroll
    for (int t4=0;t4<4;t4++) {
      int n = nbi*64 + t4*16 + c15;
      int nc = n < 4224 ? n : 4224;
      s8v bf = *(const s8v*)(attT + (((size_t)(b*4225 + nc))<<6) + kt*32 + quad*8);
      acc[t4] = __builtin_amdgcn_mfma_f32_16x16x32_bf16(a0, bf, acc[t4], 0, 0, 0);
    }
  }
  int mrow = mb*64 + wv*16 + quad*4;
  #pragma unroll
  for (int t4=0;t4<4;t4++) {
    int n2 = nbi*64 + t4*16 + c15;
    if (n2 < 4225) {
      float* op = outF + (size_t)(b*128 + mrow)*4225 + n2;
      #pragma unroll
      for (int rg=0; rg<4; rg++) op[(size_t)rg*4225] += acc[t4][rg];
    }
  }
}

extern "C" void kernel_launch(void* const* d_in, const int* in_sizes, int n_in,
                              void* d_out, int out_size, void* d_ws, size_t ws_size,
                              hipStream_t stream) {
  const float* x     = (const float*)d_in[0];
  const float* gamma = (const float*)d_in[1];
  const float* beta  = (const float*)d_in[2];
  const float* mean  = (const float*)d_in[3];
  const float* var   = (const float*)d_in[4];
  const float* w_sc  = (const float*)d_in[5];
  const float* w_q   = (const float*)d_in[6];
  const float* w_k   = (const float*)d_in[7];
  const float* w_v   = (const float*)d_in[8];
  const float* w_o   = (const float*)d_in[9];
  char* ws = (char*)d_ws;
  u16*   xrTp = (u16*)(ws + O_XRT);
  u16*   wpt  = (u16*)(ws + O_WPT);
  u16*   qhb  = (u16*)(ws + O_QH);
  u16*   kT   = (u16*)(ws + O_KT);
  u16*   vbuf = (u16*)(ws + O_V);
  u16*   attT = (u16*)(ws + O_ATT);
  u16*   wkv  = (u16*)(ws + O_WKV);
  u16*   wo2  = (u16*)(ws + O_WO2);
  float* outF = (float*)d_out;

  k_prep<<<2466, 256, 0, stream>>>(x, gamma, beta, mean, var, w_sc, w_q, w_k, w_v, w_o,
                                   xrTp, wpt, wkv, wo2);
  k_conv<<<923, 256, 0, stream>>>(xrTp, wpt, wkv, outF, qhb, kT, vbuf);
  k_attn<<<dim3(34, 32), 256, 0, stream>>>(qhb, kT, vbuf, attT);
  k_proj<<<dim3(67, 2, 4), 256, 0, stream>>>(attT, wo2, outF);
}